// Round 1
// baseline (21.600 us; speedup 1.0000x reference)
//
#include <hip/hip_runtime.h>

#define H 48
#define W 64
#define C 256
#define NK 21            // 21 displacements per axis
#define HW (H * W)       // 3072
#define ROWB (W * C)     // elements (ushort) per channels-last row slice = 16384 (32KB)

typedef __attribute__((ext_vector_type(8))) short bf16x8;
typedef __attribute__((ext_vector_type(8))) unsigned short u16x8;
typedef __attribute__((ext_vector_type(4))) float f32x4;

__device__ __forceinline__ unsigned short f2bf(float f) {
  unsigned u = __builtin_bit_cast(unsigned, f);
  u = (u + 0x7FFFu + ((u >> 16) & 1u)) >> 16;  // RNE truncate to bf16
  return (unsigned short)u;
}

// issue one 16B global->LDS DMA (wave-uniform LDS base + lane*16)
__device__ __forceinline__ void load16_to_lds(const void* g, void* l) {
  __builtin_amdgcn_global_load_lds(
      (__attribute__((address_space(1))) void*)(unsigned long long)g,
      (__attribute__((address_space(3))) void*)(unsigned int)(unsigned long long)l,
      16, 0, 0);
}

// fp32 [C][H][W] -> bf16 channels-last [H*W][C], both tensors (blockIdx.y picks)
__global__ __launch_bounds__(256) void transpose_bf16(
    const float* __restrict__ f1, const float* __restrict__ f2,
    unsigned short* __restrict__ f1t, unsigned short* __restrict__ f2t) {
  const float* src = blockIdx.y ? f2 : f1;
  unsigned short* dst = blockIdx.y ? f2t : f1t;
  int g = blockIdx.x * 256 + threadIdx.x;  // [0, HW*C/8) = 98304
  int c0 = (g & 31) << 3;
  int hw = g >> 5;
  u16x8 v;
#pragma unroll
  for (int j = 0; j < 8; ++j)
    v[j] = f2bf(src[(size_t)(c0 + j) * HW + hw]);  // strided reads, L2-friendly
  *reinterpret_cast<u16x8*>(dst + (size_t)hw * C + c0) = v;  // coalesced 16B stores
}

// One block per (y, oy) pair. Computes M[x1][x2] = sum_c f1[c,y,x1]*f2[c,r,x2]
// (64x64x256 bf16 GEMM), then extracts the 21 stride-2 diagonals.
__global__ __launch_bounds__(256, 2) void corr_mfma(
    const unsigned short* __restrict__ f1t, const unsigned short* __restrict__ f2t,
    float* __restrict__ out) {
  __shared__ char smem[65536];  // A:[0,32K) B:[32K,64K); M (64x66 f32) overlays A
  const int b = blockIdx.x;
  const int y = b / NK, oyi = b % NK;
  const int r = y + 2 * oyi - 20;
  const int tid = threadIdx.x;
  float* outBase = out + (size_t)(oyi * NK) * HW + y * W;  // + oxi*HW + x

  if ((unsigned)r >= (unsigned)H) {  // whole oy-band out of range -> zeros
    for (int i = tid; i < NK * W; i += 256) {
      int oxi = i >> 6, x = i & 63;
      outBase[(size_t)oxi * HW + x] = 0.f;
    }
    return;
  }

  const int wave = tid >> 6, lane = tid & 63;

  // ---- stage A (f1t row y) and B (f2t row r): 32KB each.
  // LDS is linear in "slot"; source is pre-swizzled so that a fragment read at
  // byte p XOR ((x&7)<<4) returns the plain element (x = p>>9). (m173 pattern)
  {
    const char* gA = (const char*)(f1t + (size_t)y * ROWB);
    const char* gB = (const char*)(f2t + (size_t)r * ROWB);
#pragma unroll
    for (int it = 0; it < 8; ++it) {
      int slot = ((it * 4 + wave) << 10) + (lane << 4);
      int src_off = slot ^ (((slot >> 9) & 7) << 4);
      load16_to_lds(gA + src_off, smem + slot);
      load16_to_lds(gB + src_off, smem + 32768 + slot);
    }
  }
  __syncthreads();

  // ---- 64x64x256 Gram via mfma_f32_16x16x32_bf16; wave w owns rows [16w,16w+16)
  f32x4 acc[4] = {};
  const int sw = (lane & 7) << 4;  // bank swizzle (x&7)<<4, tile*16 doesn't affect x&7
  const int abase = ((wave * 16 + (lane & 15)) << 9) + ((lane >> 4) << 4);
#pragma unroll
  for (int ks = 0; ks < 8; ++ks) {
    bf16x8 a = *reinterpret_cast<const bf16x8*>(smem + ((abase + (ks << 6)) ^ sw));
#pragma unroll
    for (int tn = 0; tn < 4; ++tn) {
      int baddr = ((((tn * 16 + (lane & 15)) << 9) + (ks << 6) + ((lane >> 4) << 4)) ^ sw);
      bf16x8 bb = *reinterpret_cast<const bf16x8*>(smem + 32768 + baddr);
      // A-frag: lane holds A[m=lane&15][k=(lane>>4)*8+j]; B-frag: B[k][n=lane&15]
      acc[tn] = __builtin_amdgcn_mfma_f32_16x16x32_bf16(a, bb, acc[tn], 0, 0, 0);
    }
  }
  __syncthreads();  // all reads of A-region done before overlaying with M

  // ---- write M to LDS; C/D layout: col=lane&15, row=(lane>>4)*4+reg (m89)
  float* M = (float*)smem;  // [64][66]
#pragma unroll
  for (int tn = 0; tn < 4; ++tn) {
#pragma unroll
    for (int j = 0; j < 4; ++j) {
      int x1 = (wave << 4) + ((lane >> 4) << 2) + j;
      int x2 = (tn << 4) + (lane & 15);
      M[x1 * 66 + x2] = acc[tn][j];
    }
  }
  __syncthreads();

  // ---- band extraction: out[(oyi*21+oxi), y, x] = M[x][x + 2*oxi - 20]
  for (int i = tid; i < NK * W; i += 256) {
    int oxi = i >> 6, x = i & 63;
    int x2 = x + 2 * oxi - 20;
    float v = ((unsigned)x2 < (unsigned)W) ? M[x * 66 + x2] : 0.f;
    outBase[(size_t)oxi * HW + x] = v;
  }
}

// Fallback if d_ws is too small: direct fp32, coalesced along x.
__global__ __launch_bounds__(256) void corr_direct(
    const float* __restrict__ f1, const float* __restrict__ f2, float* __restrict__ out) {
  int idx = blockIdx.x * 256 + threadIdx.x;
  if (idx >= 441 * HW) return;
  int x = idx & 63;
  int y = (idx >> 6) % H;
  int o = idx / HW;
  int oyi = o / NK, oxi = o % NK;
  int ry = y + 2 * oyi - 20, rx = x + 2 * oxi - 20;
  float acc = 0.f;
  if ((unsigned)ry < (unsigned)H && (unsigned)rx < (unsigned)W) {
    const float* p1 = f1 + y * W + x;
    const float* p2 = f2 + ry * W + rx;
#pragma unroll 8
    for (int c = 0; c < C; ++c) acc += p1[c * HW] * p2[c * HW];
  }
  out[idx] = acc;
}

extern "C" void kernel_launch(void* const* d_in, const int* in_sizes, int n_in,
                              void* d_out, int out_size, void* d_ws, size_t ws_size,
                              hipStream_t stream) {
  const float* f1 = (const float*)d_in[0];
  const float* f2 = (const float*)d_in[1];
  float* out = (float*)d_out;

  const size_t needed = 2ull * HW * C * sizeof(unsigned short);  // ~3.1 MB
  if (ws_size >= needed) {
    unsigned short* f1t = (unsigned short*)d_ws;
    unsigned short* f2t = f1t + (size_t)HW * C;
    dim3 gT((HW * C / 8 + 255) / 256, 2, 1);  // 384 x 2
    transpose_bf16<<<gT, 256, 0, stream>>>(f1, f2, f1t, f2t);
    corr_mfma<<<H * NK, 256, 0, stream>>>(f1t, f2t, out);
  } else {
    int n = 441 * HW;
    corr_direct<<<(n + 255) / 256, 256, 0, stream>>>(f1, f2, out);
  }
}

// Round 2
// 21.567 us; speedup vs baseline: 1.0016x; 1.0016x over previous
//
#include <hip/hip_runtime.h>

#define H 48
#define W 64
#define C 256
#define NK 21            // 21 displacements per axis
#define HW (H * W)       // 3072
#define ROWB (W * C)     // elements (ushort) per channels-last row slice = 16384 (32KB)

typedef __attribute__((ext_vector_type(8))) short bf16x8;
typedef __attribute__((ext_vector_type(8))) unsigned short u16x8;
typedef __attribute__((ext_vector_type(4))) float f32x4;

__device__ __forceinline__ unsigned short f2bf(float f) {
  unsigned u = __builtin_bit_cast(unsigned, f);
  u = (u + 0x7FFFu + ((u >> 16) & 1u)) >> 16;  // RNE truncate to bf16
  return (unsigned short)u;
}

// issue one 16B global->LDS DMA (wave-uniform LDS base + lane*16)
__device__ __forceinline__ void load16_to_lds(const void* g, void* l) {
  __builtin_amdgcn_global_load_lds(
      (__attribute__((address_space(1))) void*)(unsigned long long)g,
      (__attribute__((address_space(3))) void*)(unsigned int)(unsigned long long)l,
      16, 0, 0);
}

// LDS-tiled transpose: fp32 [C][HW] -> bf16 channels-last [HW][C].
// Tile = 16 c x 256 hw. Phase 1: coalesced float4 loads (1KB/wave/instr),
// 8B LDS writes. Phase 2: contiguous 2B LDS reads, 32B/thread global stores.
#define TP_HW 256
#define TP_C 16
__global__ __launch_bounds__(256) void transpose_bf16(
    const float* __restrict__ f1, const float* __restrict__ f2,
    unsigned short* __restrict__ f1t, unsigned short* __restrict__ f2t) {
  const float* src = blockIdx.z ? f2 : f1;
  unsigned short* dst = blockIdx.z ? f2t : f1t;
  const int hw0 = blockIdx.x * TP_HW;
  const int c0 = blockIdx.y * TP_C;
  __shared__ unsigned short tile[TP_C][TP_HW + 4];  // 520B row stride (8B-aligned)
  const int t = threadIdx.x;

  const int lane_hw = (t & 63) * 4;  // float4 along hw
  const int crow = t >> 6;           // wave id -> c row within group of 4
#pragma unroll
  for (int i = 0; i < 4; ++i) {
    int c_local = i * 4 + crow;
    const float* p = src + (size_t)(c0 + c_local) * HW + hw0 + lane_hw;
    float4 v = *reinterpret_cast<const float4*>(p);
    ushort4 b;
    b.x = f2bf(v.x); b.y = f2bf(v.y); b.z = f2bf(v.z); b.w = f2bf(v.w);
    *reinterpret_cast<ushort4*>(&tile[c_local][lane_hw]) = b;
  }
  __syncthreads();

  // one hw per thread; gather 16 c's (contiguous-2B LDS reads, conflict-free)
  unsigned short vals[16];
#pragma unroll
  for (int j = 0; j < 16; ++j) vals[j] = tile[j][t];
  unsigned short* o = dst + (size_t)(hw0 + t) * C + c0;
  *reinterpret_cast<u16x8*>(o) = *reinterpret_cast<const u16x8*>(&vals[0]);
  *reinterpret_cast<u16x8*>(o + 8) = *reinterpret_cast<const u16x8*>(&vals[8]);
}

// One block per (y, oy) pair. Computes M[x1][x2] = sum_c f1[c,y,x1]*f2[c,r,x2]
// (64x64x256 bf16 GEMM), then extracts the 21 stride-2 diagonals.
__global__ __launch_bounds__(256, 2) void corr_mfma(
    const unsigned short* __restrict__ f1t, const unsigned short* __restrict__ f2t,
    float* __restrict__ out) {
  __shared__ char smem[65536];  // A:[0,32K) B:[32K,64K); M (64x66 f32) overlays A
  const int b = blockIdx.x;
  const int y = b / NK, oyi = b % NK;
  const int r = y + 2 * oyi - 20;
  const int tid = threadIdx.x;
  float* outBase = out + (size_t)(oyi * NK) * HW + y * W;  // + oxi*HW + x

  if ((unsigned)r >= (unsigned)H) {  // whole oy-band out of range -> zeros
    for (int i = tid; i < NK * W; i += 256) {
      int oxi = i >> 6, x = i & 63;
      outBase[(size_t)oxi * HW + x] = 0.f;
    }
    return;
  }

  const int wave = tid >> 6, lane = tid & 63;

  // ---- stage A (f1t row y) and B (f2t row r): 32KB each.
  // LDS is linear in "slot"; source is pre-swizzled so that a fragment read at
  // byte p XOR ((x&7)<<4) returns the plain element (x = p>>9). (m173 pattern)
  {
    const char* gA = (const char*)(f1t + (size_t)y * ROWB);
    const char* gB = (const char*)(f2t + (size_t)r * ROWB);
#pragma unroll
    for (int it = 0; it < 8; ++it) {
      int slot = ((it * 4 + wave) << 10) + (lane << 4);
      int src_off = slot ^ (((slot >> 9) & 7) << 4);
      load16_to_lds(gA + src_off, smem + slot);
      load16_to_lds(gB + src_off, smem + 32768 + slot);
    }
  }
  __syncthreads();

  // ---- 64x64x256 Gram via mfma_f32_16x16x32_bf16; wave w owns rows [16w,16w+16)
  f32x4 acc[4] = {};
  const int sw = (lane & 7) << 4;  // bank swizzle (x&7)<<4, tile*16 doesn't affect x&7
  const int abase = ((wave * 16 + (lane & 15)) << 9) + ((lane >> 4) << 4);
#pragma unroll
  for (int ks = 0; ks < 8; ++ks) {
    bf16x8 a = *reinterpret_cast<const bf16x8*>(smem + ((abase + (ks << 6)) ^ sw));
#pragma unroll
    for (int tn = 0; tn < 4; ++tn) {
      int baddr = ((((tn * 16 + (lane & 15)) << 9) + (ks << 6) + ((lane >> 4) << 4)) ^ sw);
      bf16x8 bb = *reinterpret_cast<const bf16x8*>(smem + 32768 + baddr);
      // A-frag: lane holds A[m=lane&15][k=(lane>>4)*8+j]; B-frag: B[k][n=lane&15]
      acc[tn] = __builtin_amdgcn_mfma_f32_16x16x32_bf16(a, bb, acc[tn], 0, 0, 0);
    }
  }
  __syncthreads();  // all reads of A-region done before overlaying with M

  // ---- write M to LDS; C/D layout: col=lane&15, row=(lane>>4)*4+reg (m89)
  float* M = (float*)smem;  // [64][66]
#pragma unroll
  for (int tn = 0; tn < 4; ++tn) {
#pragma unroll
    for (int j = 0; j < 4; ++j) {
      int x1 = (wave << 4) + ((lane >> 4) << 2) + j;
      int x2 = (tn << 4) + (lane & 15);
      M[x1 * 66 + x2] = acc[tn][j];
    }
  }
  __syncthreads();

  // ---- band extraction: out[(oyi*21+oxi), y, x] = M[x][x + 2*oxi - 20]
  for (int i = tid; i < NK * W; i += 256) {
    int oxi = i >> 6, x = i & 63;
    int x2 = x + 2 * oxi - 20;
    float v = ((unsigned)x2 < (unsigned)W) ? M[x * 66 + x2] : 0.f;
    outBase[(size_t)oxi * HW + x] = v;
  }
}

// Fallback if d_ws is too small: direct fp32, coalesced along x.
__global__ __launch_bounds__(256) void corr_direct(
    const float* __restrict__ f1, const float* __restrict__ f2, float* __restrict__ out) {
  int idx = blockIdx.x * 256 + threadIdx.x;
  if (idx >= 441 * HW) return;
  int x = idx & 63;
  int y = (idx >> 6) % H;
  int o = idx / HW;
  int oyi = o / NK, oxi = o % NK;
  int ry = y + 2 * oyi - 20, rx = x + 2 * oxi - 20;
  float acc = 0.f;
  if ((unsigned)ry < (unsigned)H && (unsigned)rx < (unsigned)W) {
    const float* p1 = f1 + y * W + x;
    const float* p2 = f2 + ry * W + rx;
#pragma unroll 8
    for (int c = 0; c < C; ++c) acc += p1[c * HW] * p2[c * HW];
  }
  out[idx] = acc;
}

extern "C" void kernel_launch(void* const* d_in, const int* in_sizes, int n_in,
                              void* d_out, int out_size, void* d_ws, size_t ws_size,
                              hipStream_t stream) {
  const float* f1 = (const float*)d_in[0];
  const float* f2 = (const float*)d_in[1];
  float* out = (float*)d_out;

  const size_t needed = 2ull * HW * C * sizeof(unsigned short);  // ~3.1 MB
  if (ws_size >= needed) {
    unsigned short* f1t = (unsigned short*)d_ws;
    unsigned short* f2t = f1t + (size_t)HW * C;
    dim3 gT(HW / TP_HW, C / TP_C, 2);  // 12 x 16 x 2 = 384 blocks
    transpose_bf16<<<gT, 256, 0, stream>>>(f1, f2, f1t, f2t);
    corr_mfma<<<H * NK, 256, 0, stream>>>(f1t, f2t, out);
  } else {
    int n = 441 * HW;
    corr_direct<<<(n + 255) / 256, 256, 0, stream>>>(f1, f2, out);
  }
}